// Round 1
// baseline (48.032 us; speedup 1.0000x reference)
//
#include <hip/hip_runtime.h>

// PrototypeTripletRankingLoss: B=1024, K=127, D=512, fp32.
// loss = mean_b mean_k max(0, 0.2 + cos(ref_b, neg_bk) - cos(ref_b, pos_b))
// with each norm clamped to >= 1e-8 (torch cosine_similarity semantics).

#define NB 1024
#define NK 127
#define ND 512
#define MARGIN 0.2f
#define CEPS 1e-8f

__device__ __forceinline__ float dot4(const float4 a, const float4 b) {
    return a.x * b.x + a.y * b.y + a.z * b.z + a.w * b.w;
}

// One block per batch row. 256 threads = 4 waves; wave w handles k = w, w+4, ...
// Each lane owns 8 floats of the D=512 row: [lane*4 .. +3] and [256+lane*4 .. +3]
// (two fully-coalesced float4 loads per row).
__global__ __launch_bounds__(256) void triplet_main(
    const float* __restrict__ ref, const float* __restrict__ pos,
    const float* __restrict__ neg, float* __restrict__ partial)
{
    const int b    = blockIdx.x;
    const int tid  = threadIdx.x;
    const int wave = tid >> 6;
    const int lane = tid & 63;

    const float* refr = ref + (size_t)b * ND;
    const float* posr = pos + (size_t)b * ND;

    const float4 r0 = *(const float4*)(refr + lane * 4);
    const float4 r1 = *(const float4*)(refr + 256 + lane * 4);
    const float4 p0 = *(const float4*)(posr + lane * 4);
    const float4 p1 = *(const float4*)(posr + 256 + lane * 4);

    float rs = dot4(r0, r0) + dot4(r1, r1);   // ||ref||^2 partial
    float ps = dot4(p0, p0) + dot4(p1, p1);   // ||pos||^2 partial
    float pd = dot4(r0, p0) + dot4(r1, p1);   // ref.pos partial

    #pragma unroll
    for (int off = 32; off; off >>= 1) {
        rs += __shfl_xor(rs, off);
        ps += __shfl_xor(ps, off);
        pd += __shfl_xor(pd, off);
    }

    const float inv_r   = 1.0f / fmaxf(sqrtf(rs), CEPS);
    const float pos_sim = pd * inv_r * (1.0f / fmaxf(sqrtf(ps), CEPS));

    float acc = 0.0f;
    const float* negb = neg + (size_t)b * (NK * ND);
    for (int k = wave; k < NK; k += 4) {
        const float* nr = negb + (size_t)k * ND;
        const float4 n0 = *(const float4*)(nr + lane * 4);
        const float4 n1 = *(const float4*)(nr + 256 + lane * 4);
        float nd = dot4(r0, n0) + dot4(r1, n1);
        float ns = dot4(n0, n0) + dot4(n1, n1);
        #pragma unroll
        for (int off = 32; off; off >>= 1) {
            nd += __shfl_xor(nd, off);
            ns += __shfl_xor(ns, off);
        }
        const float sim = nd * inv_r * (1.0f / fmaxf(sqrtf(ns), CEPS));
        acc += fmaxf(MARGIN + sim - pos_sim, 0.0f);
    }

    // Block reduce the 4 wave accumulators (all lanes of a wave hold the same
    // butterfly-reduced values, so lane 0's acc is the wave total).
    __shared__ float sacc[4];
    if (lane == 0) sacc[wave] = acc;
    __syncthreads();
    if (tid == 0) partial[b] = (sacc[0] + sacc[1]) + (sacc[2] + sacc[3]);
}

// Deterministic final reduction: 1 block, 256 threads over 1024 partials.
__global__ __launch_bounds__(256) void triplet_reduce(
    const float* __restrict__ partial, float* __restrict__ out)
{
    float s = 0.0f;
    for (int i = threadIdx.x; i < NB; i += 256) s += partial[i];
    #pragma unroll
    for (int off = 32; off; off >>= 1) s += __shfl_xor(s, off);
    __shared__ float w[4];
    if ((threadIdx.x & 63) == 0) w[threadIdx.x >> 6] = s;
    __syncthreads();
    if (threadIdx.x == 0)
        out[0] = ((w[0] + w[1]) + (w[2] + w[3])) * (1.0f / ((float)NB * (float)NK));
}

extern "C" void kernel_launch(void* const* d_in, const int* in_sizes, int n_in,
                              void* d_out, int out_size, void* d_ws, size_t ws_size,
                              hipStream_t stream) {
    const float* ref = (const float*)d_in[0];
    const float* pos = (const float*)d_in[1];
    const float* neg = (const float*)d_in[2];
    float* out     = (float*)d_out;
    float* partial = (float*)d_ws;   // NB floats = 4 KiB scratch

    triplet_main<<<NB, 256, 0, stream>>>(ref, pos, neg, partial);
    triplet_reduce<<<1, 256, 0, stream>>>(partial, out);
}